// Round 2
// baseline (1681.001 us; speedup 1.0000x reference)
//
#include <hip/hip_runtime.h>
#include <hip/hip_bf16.h>

// Problem constants
#define BWIN 96      // b*gx*gy = 2*6*8
#define NTOK 320     // l*w1*w2 = 5*8*8
#define DIMX 256
#define HEADS 8
#define DH 32
#define INNER 256
#define CTXW 2560    // HEADS*NTOK
#define TN 8         // q-rows per attention block

// ---------------- Kernel 1: LayerNorm + QKV projection ----------------
// 8 rows per block, 256 threads. Row mapping does the
// 'b l x y w1 w2 d -> (b x y)(l w1 w2) d' rearrange on load.
__global__ __launch_bounds__(256) void k_lnqkv(
    const float* __restrict__ x, const float* __restrict__ wq,
    const float* __restrict__ wkv, const float* __restrict__ g,
    const float* __restrict__ bt, float* __restrict__ qb,
    float* __restrict__ kb, float* __restrict__ vb)
{
    __shared__ float y[8][257];
    __shared__ float redS[4], redQ[4];
    __shared__ float mv[2];
    const int t = threadIdx.x;
    const int row0 = blockIdx.x * 8;

    for (int r = 0; r < 8; ++r) {
        const int row = row0 + r;
        const int bb = row / NTOK, n = row % NTOK;
        const int b_idx = bb / 48, x_idx = (bb % 48) >> 3, y_idx = bb & 7;
        const int l_idx = n >> 6, w1_idx = (n >> 3) & 7, w2_idx = n & 7;
        const size_t src =
            ((((((size_t)b_idx * 5 + l_idx) * 6 + x_idx) * 8 + y_idx) * 8 + w1_idx) * 8 + w2_idx) * (size_t)DIMX;
        const float xv = x[src + t];
        float s = xv, ss = xv * xv;
        #pragma unroll
        for (int o = 32; o > 0; o >>= 1) {
            s += __shfl_xor(s, o);
            ss += __shfl_xor(ss, o);
        }
        if ((t & 63) == 0) { redS[t >> 6] = s; redQ[t >> 6] = ss; }
        __syncthreads();
        if (t == 0) {
            float S = redS[0] + redS[1] + redS[2] + redS[3];
            float Q = redQ[0] + redQ[1] + redQ[2] + redQ[3];
            float mu = S * (1.0f / DIMX);
            float var = Q * (1.0f / DIMX) - mu * mu;
            mv[0] = mu;
            mv[1] = rsqrtf(var + 1e-5f);
        }
        __syncthreads();
        y[r][t] = (xv - mv[0]) * mv[1] * g[t] + bt[t];
        __syncthreads();
    }

    float aq[8], ak[8], av[8];
    #pragma unroll
    for (int r = 0; r < 8; ++r) { aq[r] = 0.f; ak[r] = 0.f; av[r] = 0.f; }
    for (int d = 0; d < DIMX; ++d) {
        const float wqv = wq[d * INNER + t];
        const float wk1 = wkv[d * 512 + t];
        const float wv1 = wkv[d * 512 + 256 + t];
        #pragma unroll
        for (int r = 0; r < 8; ++r) {
            const float yv = y[r][d];   // LDS broadcast
            aq[r] = fmaf(yv, wqv, aq[r]);
            ak[r] = fmaf(yv, wk1, ak[r]);
            av[r] = fmaf(yv, wv1, av[r]);
        }
    }
    #pragma unroll
    for (int r = 0; r < 8; ++r) {
        const size_t o = (size_t)(row0 + r) * INNER + t;
        qb[o] = aq[r]; kb[o] = ak[r]; vb[o] = av[r];
    }
}

// ---------------- Kernel 2: bias attention ----------------
// grid (NTOK/TN, HEADS, BWIN), 320 threads. Thread m owns key column m.
__global__ __launch_bounds__(320) void k_attn(
    const float* __restrict__ qb, const float* __restrict__ kb,
    const float* __restrict__ vb, const float* __restrict__ ctx,
    float* __restrict__ attout)
{
    __shared__ float qv[TN][33];
    __shared__ float p[TN][321];
    __shared__ float redm[TN][5];
    __shared__ float rmax[TN], rinv[TN];
    __shared__ float part[TN][10][33];

    const int t = threadIdx.x;          // 0..319
    const int n0 = blockIdx.x * TN;
    const int h = blockIdx.y;
    const int bb = blockIdx.z;
    const int wave = t >> 6, lane = t & 63;

    // load q tile
    for (int idx = t; idx < TN * DH; idx += 320) {
        const int n = idx >> 5, dd = idx & 31;
        qv[n][dd] = qb[((size_t)bb * NTOK + n0 + n) * INNER + h * DH + dd];
    }
    __syncthreads();

    // k row of this thread into registers
    const float* krow = kb + ((size_t)bb * NTOK + t) * INNER + h * DH;
    float kreg[32];
    #pragma unroll
    for (int i = 0; i < 8; ++i) {
        const float4 kk = ((const float4*)krow)[i];
        kreg[4 * i + 0] = kk.x; kreg[4 * i + 1] = kk.y;
        kreg[4 * i + 2] = kk.z; kreg[4 * i + 3] = kk.w;
    }

    const float* crow = ctx + ((size_t)bb * NTOK + n0) * CTXW + h * NTOK + t;
    float dots[TN];
    #pragma unroll
    for (int n = 0; n < TN; ++n) {
        float a = 0.f;
        #pragma unroll
        for (int dd = 0; dd < 32; ++dd) a = fmaf(qv[n][dd], kreg[dd], a);
        dots[n] = a + crow[(size_t)n * CTXW];
    }

    // softmax over the 320 threads (m dimension)
    #pragma unroll
    for (int n = 0; n < TN; ++n) {
        float m = dots[n];
        #pragma unroll
        for (int o = 32; o > 0; o >>= 1) m = fmaxf(m, __shfl_xor(m, o));
        if (lane == 0) redm[n][wave] = m;
    }
    __syncthreads();
    if (t < TN) {
        float m = redm[t][0];
        #pragma unroll
        for (int w = 1; w < 5; ++w) m = fmaxf(m, redm[t][w]);
        rmax[t] = m;
    }
    __syncthreads();
    #pragma unroll
    for (int n = 0; n < TN; ++n) {
        float e = __expf(dots[n] - rmax[n]);
        p[n][t] = e;
        #pragma unroll
        for (int o = 32; o > 0; o >>= 1) e += __shfl_xor(e, o);
        if (lane == 0) redm[n][wave] = e;
    }
    __syncthreads();
    if (t < TN) {
        float s2 = redm[t][0] + redm[t][1] + redm[t][2] + redm[t][3] + redm[t][4];
        rinv[t] = 1.0f / s2;
    }
    __syncthreads();

    // PV: thread (chunk = t>>5, d = t&31) accumulates 32 keys for all TN rows
    const int d = t & 31, chunk = t >> 5;
    const float* vbase = vb + ((size_t)bb * NTOK + chunk * 32) * INNER + h * DH + d;
    float vreg[32];
    #pragma unroll
    for (int j = 0; j < 32; ++j) vreg[j] = vbase[(size_t)j * INNER];
    #pragma unroll
    for (int n = 0; n < TN; ++n) {
        float a = 0.f;
        #pragma unroll
        for (int j = 0; j < 32; ++j) a = fmaf(p[n][chunk * 32 + j], vreg[j], a);
        part[n][chunk][d] = a;
    }
    __syncthreads();
    for (int idx = t; idx < TN * DH; idx += 320) {
        const int n = idx >> 5, dd = idx & 31;
        float a = 0.f;
        #pragma unroll
        for (int c = 0; c < 10; ++c) a += part[n][c][dd];
        attout[((size_t)bb * NTOK + n0 + n) * INNER + h * DH + dd] = a * rinv[n];
    }
}

// ---------------- Kernel 3: output projection + re-scatter ----------------
__global__ __launch_bounds__(256) void k_out(
    const float* __restrict__ attout, const float* __restrict__ wout,
    float* __restrict__ out)
{
    const int t = threadIdx.x;
    const int r = t >> 5, d = t & 31;
    const int row = blockIdx.x * 8 + r;
    const float* arow = attout + (size_t)row * INNER;
    float acc = 0.f;
    for (int c = 0; c < INNER; ++c) acc = fmaf(arow[c], wout[c * DH + d], acc);
    const int bb = row / NTOK, n = row % NTOK;
    const int b_idx = bb / 48, x_idx = (bb % 48) >> 3, y_idx = bb & 7;
    const int l_idx = n >> 6, w1_idx = (n >> 3) & 7, w2_idx = n & 7;
    const size_t dst =
        ((((((size_t)b_idx * 5 + l_idx) * 6 + x_idx) * 8 + y_idx) * 8 + w1_idx) * 8 + w2_idx) * (size_t)DH + d;
    out[dst] = acc;
}

extern "C" void kernel_launch(void* const* d_in, const int* in_sizes, int n_in,
                              void* d_out, int out_size, void* d_ws, size_t ws_size,
                              hipStream_t stream) {
    const float* x    = (const float*)d_in[0];
    const float* ctx  = (const float*)d_in[1];
    const float* wq   = (const float*)d_in[2];
    const float* wkv  = (const float*)d_in[3];
    const float* wout = (const float*)d_in[4];
    const float* ln_g = (const float*)d_in[5];
    const float* ln_b = (const float*)d_in[6];
    float* out = (float*)d_out;

    // workspace layout: q | k | v | attout, each BWIN*NTOK*INNER floats
    const size_t SEG = (size_t)BWIN * NTOK * INNER;  // 7,864,320 floats
    float* qb = (float*)d_ws;
    float* kb = qb + SEG;
    float* vb = kb + SEG;
    float* ao = vb + SEG;

    const int ROWS = BWIN * NTOK;  // 30720
    k_lnqkv<<<ROWS / 8, 256, 0, stream>>>(x, wq, wkv, ln_g, ln_b, qb, kb, vb);
    k_attn<<<dim3(NTOK / TN, HEADS, BWIN), 320, 0, stream>>>(qb, kb, vb, ctx, ao);
    k_out<<<ROWS / 8, 256, 0, stream>>>(ao, wout, out);
}

// Round 3
// 370.904 us; speedup vs baseline: 4.5322x; 4.5322x over previous
//
#include <hip/hip_runtime.h>
#include <hip/hip_bf16.h>

// Problem constants
#define BWIN 96      // b*gx*gy = 2*6*8
#define NTOK 320     // l*w1*w2 = 5*8*8
#define DIMX 256
#define HEADS 8
#define DH 32
#define INNER 256
#define CTXW 2560    // HEADS*NTOK
#define MPAD 328     // padded m-stride (bf16) for P/V^T LDS: 656B row = 16B-aligned, 2-way banks

typedef __bf16 bf16x8 __attribute__((ext_vector_type(8)));
typedef float f32x4 __attribute__((ext_vector_type(4)));

// ---------------- Kernel 1: LayerNorm + QKV projection (bf16 out) ----------------
// 16 rows per block, 256 threads.
__global__ __launch_bounds__(256) void k_lnqkv(
    const float* __restrict__ x, const float* __restrict__ wq,
    const float* __restrict__ wkv, const float* __restrict__ g,
    const float* __restrict__ bt, __hip_bfloat16* __restrict__ qb,
    __hip_bfloat16* __restrict__ kb, __hip_bfloat16* __restrict__ vb)
{
    __shared__ float y[16][257];
    __shared__ float redS[4], redQ[4];
    __shared__ float mv[2];
    const int t = threadIdx.x;
    const int row0 = blockIdx.x * 16;

    for (int r = 0; r < 16; ++r) {
        const int row = row0 + r;
        const int bb = row / NTOK, n = row % NTOK;
        const int b_idx = bb / 48, x_idx = (bb % 48) >> 3, y_idx = bb & 7;
        const int l_idx = n >> 6, w1_idx = (n >> 3) & 7, w2_idx = n & 7;
        const size_t src =
            ((((((size_t)b_idx * 5 + l_idx) * 6 + x_idx) * 8 + y_idx) * 8 + w1_idx) * 8 + w2_idx) * (size_t)DIMX;
        const float xv = x[src + t];
        float s = xv, ss = xv * xv;
        #pragma unroll
        for (int o = 32; o > 0; o >>= 1) {
            s += __shfl_xor(s, o);
            ss += __shfl_xor(ss, o);
        }
        if ((t & 63) == 0) { redS[t >> 6] = s; redQ[t >> 6] = ss; }
        __syncthreads();
        if (t == 0) {
            float S = redS[0] + redS[1] + redS[2] + redS[3];
            float Q = redQ[0] + redQ[1] + redQ[2] + redQ[3];
            float mu = S * (1.0f / DIMX);
            float var = Q * (1.0f / DIMX) - mu * mu;
            mv[0] = mu;
            mv[1] = rsqrtf(var + 1e-5f);
        }
        __syncthreads();
        y[r][t] = (xv - mv[0]) * mv[1] * g[t] + bt[t];
        __syncthreads();
    }

    float aq[16], ak[16], av[16];
    #pragma unroll
    for (int r = 0; r < 16; ++r) { aq[r] = 0.f; ak[r] = 0.f; av[r] = 0.f; }
    for (int d = 0; d < DIMX; ++d) {
        const float wqv = wq[d * INNER + t];
        const float wk1 = wkv[d * 512 + t];
        const float wv1 = wkv[d * 512 + 256 + t];
        #pragma unroll
        for (int r = 0; r < 16; ++r) {
            const float yv = y[r][d];   // LDS broadcast
            aq[r] = fmaf(yv, wqv, aq[r]);
            ak[r] = fmaf(yv, wk1, ak[r]);
            av[r] = fmaf(yv, wv1, av[r]);
        }
    }
    #pragma unroll
    for (int r = 0; r < 16; ++r) {
        const size_t o = (size_t)(row0 + r) * INNER + t;
        qb[o] = __float2bfloat16(aq[r]);
        kb[o] = __float2bfloat16(ak[r]);
        vb[o] = __float2bfloat16(av[r]);
    }
}

// ---------------- Kernel 2: MFMA bias attention ----------------
// grid (5, HEADS, BWIN): block = 4 waves = 256 threads; each block handles a
// 64-row q tile vs all 320 keys of one (window, head).
// Fragment conventions (m89/m92-verified):
//   A-frag 16x16x32: lane holds A[row=l&15][k=(l>>4)*8+j], 8 contiguous bf16
//   B-frag:          lane holds B[k=(l>>4)*8+j][col=l&15]
//   D:               lane holds D[row=(l>>4)*4+i][col=l&15]
__global__ __launch_bounds__(256) void k_attn_mfma(
    const __bf16* __restrict__ qb, const __bf16* __restrict__ kb,
    const __bf16* __restrict__ vb, const float* __restrict__ ctx,
    float* __restrict__ attout)
{
    __shared__ __bf16 vt[DH][MPAD];        // V^T: [d][m]
    __shared__ __bf16 plds[4][16][MPAD];   // per-wave P strip [n][m]

    const int t = threadIdx.x;
    const int wave = t >> 6, lane = t & 63;
    const int lr = lane & 15, lg = lane >> 4;
    const int n0 = blockIdx.x * 64;
    const int h = blockIdx.y, bb = blockIdx.z;
    const int nw = n0 + wave * 16;         // this wave's 16 q rows

    // --- stage V^T (fp-free: bf16 global -> transposed bf16 LDS) ---
    {
        const __bf16* vsrc = vb + ((size_t)bb * NTOK) * INNER + h * DH;
        for (int idx = t; idx < NTOK * 4; idx += 256) {
            const int m = idx >> 2, c = idx & 3;
            const bf16x8 v8 = *(const bf16x8*)(vsrc + (size_t)m * INNER + c * 8);
            #pragma unroll
            for (int j = 0; j < 8; ++j) vt[c * 8 + j][m] = v8[j];
        }
    }

    // --- Q A-fragment (direct global, 16B/lane) ---
    const bf16x8 qfrag =
        *(const bf16x8*)(qb + ((size_t)(bb * NTOK + nw + lr)) * INNER + h * DH + lg * 8);

    // --- QK^T: 20 column tiles of 16 keys ---
    f32x4 s[20];
    {
        const __bf16* kbase = kb + ((size_t)(bb * NTOK)) * INNER + h * DH + lg * 8;
        #pragma unroll
        for (int mt = 0; mt < 20; ++mt) {
            const bf16x8 kfrag = *(const bf16x8*)(kbase + (size_t)(mt * 16 + lr) * INNER);
            s[mt] = __builtin_amdgcn_mfma_f32_16x16x32_bf16(qfrag, kfrag,
                                                            (f32x4){0.f, 0.f, 0.f, 0.f}, 0, 0, 0);
        }
    }

    // --- add bias at D-fragment positions ---
    {
        const float* cbase = ctx + ((size_t)(bb * NTOK + nw)) * CTXW + h * NTOK;
        #pragma unroll
        for (int i = 0; i < 4; ++i) {
            const float* crow = cbase + (size_t)(lg * 4 + i) * CTXW + lr;
            #pragma unroll
            for (int mt = 0; mt < 20; ++mt) s[mt][i] += crow[mt * 16];
        }
    }

    // --- softmax over m (20 tiles x 16 lanes of lr) ---
    float rmax[4], rsum[4], rinv[4];
    #pragma unroll
    for (int i = 0; i < 4; ++i) rmax[i] = -3e38f;
    #pragma unroll
    for (int mt = 0; mt < 20; ++mt)
        #pragma unroll
        for (int i = 0; i < 4; ++i) rmax[i] = fmaxf(rmax[i], s[mt][i]);
    #pragma unroll
    for (int i = 0; i < 4; ++i)
        #pragma unroll
        for (int o = 1; o <= 8; o <<= 1) rmax[i] = fmaxf(rmax[i], __shfl_xor(rmax[i], o));
    #pragma unroll
    for (int i = 0; i < 4; ++i) rsum[i] = 0.f;
    #pragma unroll
    for (int mt = 0; mt < 20; ++mt)
        #pragma unroll
        for (int i = 0; i < 4; ++i) {
            const float e = __expf(s[mt][i] - rmax[i]);
            s[mt][i] = e;
            rsum[i] += e;
        }
    #pragma unroll
    for (int i = 0; i < 4; ++i) {
        #pragma unroll
        for (int o = 1; o <= 8; o <<= 1) rsum[i] += __shfl_xor(rsum[i], o);
        rinv[i] = 1.0f / rsum[i];
    }

    // --- P (bf16) to LDS in row-major [n][m] for A-fragment reads ---
    #pragma unroll
    for (int mt = 0; mt < 20; ++mt)
        #pragma unroll
        for (int i = 0; i < 4; ++i)
            plds[wave][lg * 4 + i][mt * 16 + lr] = (__bf16)s[mt][i];

    __syncthreads();   // covers V^T staging (and P, though P is wave-private)

    // --- PV: O[16 x 32] per wave, K-dim = 320 in 10 steps of 32 ---
    f32x4 o0 = {0.f, 0.f, 0.f, 0.f}, o1 = {0.f, 0.f, 0.f, 0.f};
    #pragma unroll
    for (int ks = 0; ks < 10; ++ks) {
        const bf16x8 pfrag = *(const bf16x8*)&plds[wave][lr][ks * 32 + lg * 8];
        const bf16x8 vf0 = *(const bf16x8*)&vt[lr][ks * 32 + lg * 8];
        const bf16x8 vf1 = *(const bf16x8*)&vt[16 + lr][ks * 32 + lg * 8];
        o0 = __builtin_amdgcn_mfma_f32_16x16x32_bf16(pfrag, vf0, o0, 0, 0, 0);
        o1 = __builtin_amdgcn_mfma_f32_16x16x32_bf16(pfrag, vf1, o1, 0, 0, 0);
    }

    // --- write O (normalize by row sum) ---
    {
        float* obase = attout + ((size_t)(bb * NTOK + nw)) * INNER + h * DH;
        #pragma unroll
        for (int i = 0; i < 4; ++i) {
            float* orow = obase + (size_t)(lg * 4 + i) * INNER + lr;
            orow[0]  = o0[i] * rinv[i];
            orow[16] = o1[i] * rinv[i];
        }
    }
}

// ---------------- Kernel 3: output projection + re-scatter ----------------
__global__ __launch_bounds__(256) void k_out(
    const float* __restrict__ attout, const float* __restrict__ wout,
    float* __restrict__ out)
{
    const int t = threadIdx.x;
    const int r = t >> 5, d = t & 31;
    const int row = blockIdx.x * 8 + r;
    const float* arow = attout + (size_t)row * INNER;
    float acc = 0.f;
    for (int c = 0; c < INNER; ++c) acc = fmaf(arow[c], wout[c * DH + d], acc);
    const int bb = row / NTOK, n = row % NTOK;
    const int b_idx = bb / 48, x_idx = (bb % 48) >> 3, y_idx = bb & 7;
    const int l_idx = n >> 6, w1_idx = (n >> 3) & 7, w2_idx = n & 7;
    const size_t dst =
        ((((((size_t)b_idx * 5 + l_idx) * 6 + x_idx) * 8 + y_idx) * 8 + w1_idx) * 8 + w2_idx) * (size_t)DH + d;
    out[dst] = acc;
}

extern "C" void kernel_launch(void* const* d_in, const int* in_sizes, int n_in,
                              void* d_out, int out_size, void* d_ws, size_t ws_size,
                              hipStream_t stream) {
    const float* x    = (const float*)d_in[0];
    const float* ctx  = (const float*)d_in[1];
    const float* wq   = (const float*)d_in[2];
    const float* wkv  = (const float*)d_in[3];
    const float* wout = (const float*)d_in[4];
    const float* ln_g = (const float*)d_in[5];
    const float* ln_b = (const float*)d_in[6];
    float* out = (float*)d_out;

    // workspace: q|k|v bf16 (15 MB each) then attout fp32 (31.5 MB)
    const size_t SEG = (size_t)BWIN * NTOK * INNER;  // 7,864,320 elements
    __hip_bfloat16* qb = (__hip_bfloat16*)d_ws;
    __hip_bfloat16* kb = qb + SEG;
    __hip_bfloat16* vb = kb + SEG;
    float* ao = (float*)(vb + SEG);

    const int ROWS = BWIN * NTOK;  // 30720
    k_lnqkv<<<ROWS / 16, 256, 0, stream>>>(x, wq, wkv, ln_g, ln_b, qb, kb, vb);
    k_attn_mfma<<<dim3(NTOK / 64, HEADS, BWIN), 256, 0, stream>>>(
        (const __bf16*)qb, (const __bf16*)kb, (const __bf16*)vb, ctx, ao);
    k_out<<<ROWS / 8, 256, 0, stream>>>(ao, wout, out);
}

// Round 4
// 284.281 us; speedup vs baseline: 5.9132x; 1.3047x over previous
//
#include <hip/hip_runtime.h>
#include <hip/hip_bf16.h>

// Problem constants
#define BWIN 96      // b*gx*gy = 2*6*8
#define NTOK 320     // l*w1*w2 = 5*8*8
#define DIMX 256
#define HEADS 8
#define DH 32
#define INNER 256
#define CTXW 2560    // HEADS*NTOK
#define MPAD 328     // padded m-stride (bf16) for P/V^T LDS

typedef __bf16 bf16x8 __attribute__((ext_vector_type(8)));
typedef __bf16 bf16x4 __attribute__((ext_vector_type(4)));
typedef float f32x4 __attribute__((ext_vector_type(4)));

// ---------------- Kernel 0: weight cast+transpose -> wT[768][256] bf16 ----------------
// col 0..255 = q, 256..511 = k, 512..767 = v. wT[col][d] contiguous along d(=K).
__global__ __launch_bounds__(256) void k_castw(
    const float* __restrict__ wq, const float* __restrict__ wkv,
    __bf16* __restrict__ wT)
{
    const int col = blockIdx.x, d = threadIdx.x;
    float v;
    if (col < 256)      v = wq[d * 256 + col];
    else if (col < 512) v = wkv[d * 512 + (col - 256)];
    else                v = wkv[d * 512 + 256 + (col - 512)];
    wT[(size_t)col * 256 + d] = (__bf16)v;
}

// ---------------- Kernel 1: LayerNorm -> y bf16 [30720][256] ----------------
// One row per wave (4 rows / 256-thread block). Rearrange gather on load.
__global__ __launch_bounds__(256) void k_ln(
    const float* __restrict__ x, const float* __restrict__ g,
    const float* __restrict__ bt, __bf16* __restrict__ y)
{
    const int t = threadIdx.x, wave = t >> 6, lane = t & 63;
    const int row = blockIdx.x * 4 + wave;
    const int bb = row / NTOK, n = row % NTOK;
    const int b_idx = bb / 48, x_idx = (bb % 48) >> 3, y_idx = bb & 7;
    const int l_idx = n >> 6, w1_idx = (n >> 3) & 7, w2_idx = n & 7;
    const size_t src =
        ((((((size_t)b_idx * 5 + l_idx) * 6 + x_idx) * 8 + y_idx) * 8 + w1_idx) * 8 + w2_idx) * (size_t)DIMX;

    const float4 xv = *(const float4*)(x + src + lane * 4);
    float s = xv.x + xv.y + xv.z + xv.w;
    float ss = xv.x * xv.x + xv.y * xv.y + xv.z * xv.z + xv.w * xv.w;
    #pragma unroll
    for (int o = 32; o > 0; o >>= 1) {
        s += __shfl_xor(s, o);
        ss += __shfl_xor(ss, o);
    }
    const float mu = s * (1.0f / DIMX);
    const float var = ss * (1.0f / DIMX) - mu * mu;
    const float rsig = rsqrtf(var + 1e-5f);
    const float4 g4 = *(const float4*)(g + lane * 4);
    const float4 b4 = *(const float4*)(bt + lane * 4);
    bf16x4 yo;
    yo[0] = (__bf16)((xv.x - mu) * rsig * g4.x + b4.x);
    yo[1] = (__bf16)((xv.y - mu) * rsig * g4.y + b4.y);
    yo[2] = (__bf16)((xv.z - mu) * rsig * g4.z + b4.z);
    yo[3] = (__bf16)((xv.w - mu) * rsig * g4.w + b4.w);
    *(bf16x4*)(y + (size_t)row * DIMX + lane * 4) = yo;
}

// ---------------- Kernel 2: QKV projection GEMM (bf16 MFMA) ----------------
// grid (480, 3): 64-row M-tile x one 256-col chunk (q / k / v).
// 4 waves; wave owns 16 rows x 256 cols = 16 acc tiles; K=256 in 8 steps.
__global__ __launch_bounds__(256) void k_qkv(
    const __bf16* __restrict__ y, const __bf16* __restrict__ wT,
    __bf16* __restrict__ qb, __bf16* __restrict__ kb, __bf16* __restrict__ vb)
{
    __shared__ __bf16 ytile[4][16][264];
    const int t = threadIdx.x, wave = t >> 6, lane = t & 63;
    const int lr = lane & 15, lg = lane >> 4;
    const int m0 = blockIdx.x * 64;
    const int nc = blockIdx.y;

    const __bf16* A = y + (size_t)(m0 + wave * 16 + lr) * DIMX + lg * 8;
    const __bf16* B = wT + (size_t)(nc * 256 + lr) * DIMX + lg * 8;

    f32x4 acc[16];
    #pragma unroll
    for (int ct = 0; ct < 16; ++ct) acc[ct] = (f32x4){0.f, 0.f, 0.f, 0.f};

    #pragma unroll
    for (int ks = 0; ks < 8; ++ks) {
        const bf16x8 af = *(const bf16x8*)(A + ks * 32);
        #pragma unroll
        for (int ct = 0; ct < 16; ++ct) {
            const bf16x8 bfr = *(const bf16x8*)(B + (size_t)ct * 16 * DIMX + ks * 32);
            acc[ct] = __builtin_amdgcn_mfma_f32_16x16x32_bf16(af, bfr, acc[ct], 0, 0, 0);
        }
    }

    // repack via LDS for coalesced stores
    #pragma unroll
    for (int ct = 0; ct < 16; ++ct)
        #pragma unroll
        for (int i = 0; i < 4; ++i)
            ytile[wave][lg * 4 + i][ct * 16 + lr] = (__bf16)acc[ct][i];
    __syncthreads();

    __bf16* out = (nc == 0) ? qb : (nc == 1) ? kb : vb;
    const int row = t >> 2, qtr = t & 3;
    const __bf16* srcp = &ytile[row >> 4][row & 15][qtr * 64];
    __bf16* dst = out + (size_t)(m0 + row) * 256 + qtr * 64;
    #pragma unroll
    for (int j = 0; j < 8; ++j)
        *(bf16x8*)(dst + j * 8) = *(const bf16x8*)(srcp + j * 8);
}

// ---------------- Kernel 3: MFMA bias attention (unchanged) ----------------
__global__ __launch_bounds__(256) void k_attn_mfma(
    const __bf16* __restrict__ qb, const __bf16* __restrict__ kb,
    const __bf16* __restrict__ vb, const float* __restrict__ ctx,
    float* __restrict__ attout)
{
    __shared__ __bf16 vt[DH][MPAD];        // V^T: [d][m]
    __shared__ __bf16 plds[4][16][MPAD];   // per-wave P strip [n][m]

    const int t = threadIdx.x;
    const int wave = t >> 6, lane = t & 63;
    const int lr = lane & 15, lg = lane >> 4;
    const int n0 = blockIdx.x * 64;
    const int h = blockIdx.y, bb = blockIdx.z;
    const int nw = n0 + wave * 16;

    {
        const __bf16* vsrc = vb + ((size_t)bb * NTOK) * INNER + h * DH;
        for (int idx = t; idx < NTOK * 4; idx += 256) {
            const int m = idx >> 2, c = idx & 3;
            const bf16x8 v8 = *(const bf16x8*)(vsrc + (size_t)m * INNER + c * 8);
            #pragma unroll
            for (int j = 0; j < 8; ++j) vt[c * 8 + j][m] = v8[j];
        }
    }

    const bf16x8 qfrag =
        *(const bf16x8*)(qb + ((size_t)(bb * NTOK + nw + lr)) * INNER + h * DH + lg * 8);

    f32x4 s[20];
    {
        const __bf16* kbase = kb + ((size_t)(bb * NTOK)) * INNER + h * DH + lg * 8;
        #pragma unroll
        for (int mt = 0; mt < 20; ++mt) {
            const bf16x8 kfrag = *(const bf16x8*)(kbase + (size_t)(mt * 16 + lr) * INNER);
            s[mt] = __builtin_amdgcn_mfma_f32_16x16x32_bf16(qfrag, kfrag,
                                                            (f32x4){0.f, 0.f, 0.f, 0.f}, 0, 0, 0);
        }
    }

    {
        const float* cbase = ctx + ((size_t)(bb * NTOK + nw)) * CTXW + h * NTOK;
        #pragma unroll
        for (int i = 0; i < 4; ++i) {
            const float* crow = cbase + (size_t)(lg * 4 + i) * CTXW + lr;
            #pragma unroll
            for (int mt = 0; mt < 20; ++mt) s[mt][i] += crow[mt * 16];
        }
    }

    float rmax[4], rsum[4], rinv[4];
    #pragma unroll
    for (int i = 0; i < 4; ++i) rmax[i] = -3e38f;
    #pragma unroll
    for (int mt = 0; mt < 20; ++mt)
        #pragma unroll
        for (int i = 0; i < 4; ++i) rmax[i] = fmaxf(rmax[i], s[mt][i]);
    #pragma unroll
    for (int i = 0; i < 4; ++i)
        #pragma unroll
        for (int o = 1; o <= 8; o <<= 1) rmax[i] = fmaxf(rmax[i], __shfl_xor(rmax[i], o));
    #pragma unroll
    for (int i = 0; i < 4; ++i) rsum[i] = 0.f;
    #pragma unroll
    for (int mt = 0; mt < 20; ++mt)
        #pragma unroll
        for (int i = 0; i < 4; ++i) {
            const float e = __expf(s[mt][i] - rmax[i]);
            s[mt][i] = e;
            rsum[i] += e;
        }
    #pragma unroll
    for (int i = 0; i < 4; ++i) {
        #pragma unroll
        for (int o = 1; o <= 8; o <<= 1) rsum[i] += __shfl_xor(rsum[i], o);
        rinv[i] = 1.0f / rsum[i];
    }

    #pragma unroll
    for (int mt = 0; mt < 20; ++mt)
        #pragma unroll
        for (int i = 0; i < 4; ++i)
            plds[wave][lg * 4 + i][mt * 16 + lr] = (__bf16)s[mt][i];

    __syncthreads();

    f32x4 o0 = {0.f, 0.f, 0.f, 0.f}, o1 = {0.f, 0.f, 0.f, 0.f};
    #pragma unroll
    for (int ks = 0; ks < 10; ++ks) {
        const bf16x8 pfrag = *(const bf16x8*)&plds[wave][lr][ks * 32 + lg * 8];
        const bf16x8 vf0 = *(const bf16x8*)&vt[lr][ks * 32 + lg * 8];
        const bf16x8 vf1 = *(const bf16x8*)&vt[16 + lr][ks * 32 + lg * 8];
        o0 = __builtin_amdgcn_mfma_f32_16x16x32_bf16(pfrag, vf0, o0, 0, 0, 0);
        o1 = __builtin_amdgcn_mfma_f32_16x16x32_bf16(pfrag, vf1, o1, 0, 0, 0);
    }

    {
        float* obase = attout + ((size_t)(bb * NTOK + nw)) * INNER + h * DH;
        #pragma unroll
        for (int i = 0; i < 4; ++i) {
            float* orow = obase + (size_t)(lg * 4 + i) * INNER + lr;
            orow[0]  = o0[i] * rinv[i];
            orow[16] = o1[i] * rinv[i];
        }
    }
}

// ---------------- Kernel 4: output projection + re-scatter ----------------
__global__ __launch_bounds__(256) void k_out(
    const float* __restrict__ attout, const float* __restrict__ wout,
    float* __restrict__ out)
{
    const int t = threadIdx.x;
    const int r = t >> 5, d = t & 31;
    const int row = blockIdx.x * 8 + r;
    const float* arow = attout + (size_t)row * INNER;
    float acc = 0.f;
    for (int c = 0; c < INNER; ++c) acc = fmaf(arow[c], wout[c * DH + d], acc);
    const int bb = row / NTOK, n = row % NTOK;
    const int b_idx = bb / 48, x_idx = (bb % 48) >> 3, y_idx = bb & 7;
    const int l_idx = n >> 6, w1_idx = (n >> 3) & 7, w2_idx = n & 7;
    const size_t dst =
        ((((((size_t)b_idx * 5 + l_idx) * 6 + x_idx) * 8 + y_idx) * 8 + w1_idx) * 8 + w2_idx) * (size_t)DH + d;
    out[dst] = acc;
}

extern "C" void kernel_launch(void* const* d_in, const int* in_sizes, int n_in,
                              void* d_out, int out_size, void* d_ws, size_t ws_size,
                              hipStream_t stream) {
    const float* x    = (const float*)d_in[0];
    const float* ctx  = (const float*)d_in[1];
    const float* wq   = (const float*)d_in[2];
    const float* wkv  = (const float*)d_in[3];
    const float* wout = (const float*)d_in[4];
    const float* ln_g = (const float*)d_in[5];
    const float* ln_b = (const float*)d_in[6];
    float* out = (float*)d_out;

    // workspace: qb|kb|vb bf16, ao f32, y bf16, wT bf16  (~95 MB total)
    const size_t SEG = (size_t)BWIN * NTOK * INNER;  // 7,864,320 elements
    __bf16* qb = (__bf16*)d_ws;
    __bf16* kb = qb + SEG;
    __bf16* vb = kb + SEG;
    float*  ao = (float*)(vb + SEG);
    __bf16* yb = (__bf16*)(ao + SEG);
    __bf16* wT = yb + SEG;

    const int ROWS = BWIN * NTOK;  // 30720
    k_castw<<<768, 256, 0, stream>>>(wq, wkv, wT);
    k_ln<<<ROWS / 4, 256, 0, stream>>>(x, ln_g, ln_b, yb);
    k_qkv<<<dim3(ROWS / 64, 3), 256, 0, stream>>>(yb, wT, qb, kb, vb);
    k_attn_mfma<<<dim3(NTOK / 64, HEADS, BWIN), 256, 0, stream>>>(
        (const __bf16*)qb, (const __bf16*)kb, (const __bf16*)vb, ctx, ao);
    k_out<<<ROWS / 8, 256, 0, stream>>>(ao, wout, out);
}

// Round 5
// 275.844 us; speedup vs baseline: 6.0940x; 1.0306x over previous
//
#include <hip/hip_runtime.h>
#include <hip/hip_bf16.h>

// Problem constants
#define BWIN 96      // b*gx*gy = 2*6*8
#define NTOK 320     // l*w1*w2 = 5*8*8
#define DIMX 256
#define HEADS 8
#define DH 32
#define INNER 256
#define CTXW 2560    // HEADS*NTOK
#define MPAD 328     // padded m-stride (bf16) for P LDS

typedef __bf16 bf16x8 __attribute__((ext_vector_type(8)));
typedef __bf16 bf16x4 __attribute__((ext_vector_type(4)));
typedef float f32x4 __attribute__((ext_vector_type(4)));

// ---------------- Kernel 0: weight cast+transpose -> wT[768][256] bf16 ----------------
__global__ __launch_bounds__(256) void k_castw(
    const float* __restrict__ wq, const float* __restrict__ wkv,
    __bf16* __restrict__ wT)
{
    const int col = blockIdx.x, d = threadIdx.x;
    float v;
    if (col < 256)      v = wq[d * 256 + col];
    else if (col < 512) v = wkv[d * 512 + (col - 256)];
    else                v = wkv[d * 512 + 256 + (col - 512)];
    wT[(size_t)col * 256 + d] = (__bf16)v;
}

// ---------------- Kernel 1: LayerNorm -> y bf16 [30720][256] ----------------
__global__ __launch_bounds__(256) void k_ln(
    const float* __restrict__ x, const float* __restrict__ g,
    const float* __restrict__ bt, __bf16* __restrict__ y)
{
    const int t = threadIdx.x, wave = t >> 6, lane = t & 63;
    const int row = blockIdx.x * 4 + wave;
    const int bb = row / NTOK, n = row % NTOK;
    const int b_idx = bb / 48, x_idx = (bb % 48) >> 3, y_idx = bb & 7;
    const int l_idx = n >> 6, w1_idx = (n >> 3) & 7, w2_idx = n & 7;
    const size_t src =
        ((((((size_t)b_idx * 5 + l_idx) * 6 + x_idx) * 8 + y_idx) * 8 + w1_idx) * 8 + w2_idx) * (size_t)DIMX;

    const float4 xv = *(const float4*)(x + src + lane * 4);
    float s = xv.x + xv.y + xv.z + xv.w;
    float ss = xv.x * xv.x + xv.y * xv.y + xv.z * xv.z + xv.w * xv.w;
    #pragma unroll
    for (int o = 32; o > 0; o >>= 1) {
        s += __shfl_xor(s, o);
        ss += __shfl_xor(ss, o);
    }
    const float mu = s * (1.0f / DIMX);
    const float var = ss * (1.0f / DIMX) - mu * mu;
    const float rsig = rsqrtf(var + 1e-5f);
    const float4 g4 = *(const float4*)(g + lane * 4);
    const float4 b4 = *(const float4*)(bt + lane * 4);
    bf16x4 yo;
    yo[0] = (__bf16)((xv.x - mu) * rsig * g4.x + b4.x);
    yo[1] = (__bf16)((xv.y - mu) * rsig * g4.y + b4.y);
    yo[2] = (__bf16)((xv.z - mu) * rsig * g4.z + b4.z);
    yo[3] = (__bf16)((xv.w - mu) * rsig * g4.w + b4.w);
    *(bf16x4*)(y + (size_t)row * DIMX + lane * 4) = yo;
}

// ---------------- Kernel 2: QKV projection GEMM (bf16 MFMA) ----------------
__global__ __launch_bounds__(256) void k_qkv(
    const __bf16* __restrict__ y, const __bf16* __restrict__ wT,
    __bf16* __restrict__ qb, __bf16* __restrict__ kb, __bf16* __restrict__ vb)
{
    __shared__ __bf16 ytile[4][16][264];
    const int t = threadIdx.x, wave = t >> 6, lane = t & 63;
    const int lr = lane & 15, lg = lane >> 4;
    const int m0 = blockIdx.x * 64;
    const int nc = blockIdx.y;

    const __bf16* A = y + (size_t)(m0 + wave * 16 + lr) * DIMX + lg * 8;
    const __bf16* B = wT + (size_t)(nc * 256 + lr) * DIMX + lg * 8;

    f32x4 acc[16];
    #pragma unroll
    for (int ct = 0; ct < 16; ++ct) acc[ct] = (f32x4){0.f, 0.f, 0.f, 0.f};

    #pragma unroll
    for (int ks = 0; ks < 8; ++ks) {
        const bf16x8 af = *(const bf16x8*)(A + ks * 32);
        #pragma unroll
        for (int ct = 0; ct < 16; ++ct) {
            const bf16x8 bfr = *(const bf16x8*)(B + (size_t)ct * 16 * DIMX + ks * 32);
            acc[ct] = __builtin_amdgcn_mfma_f32_16x16x32_bf16(af, bfr, acc[ct], 0, 0, 0);
        }
    }

    #pragma unroll
    for (int ct = 0; ct < 16; ++ct)
        #pragma unroll
        for (int i = 0; i < 4; ++i)
            ytile[wave][lg * 4 + i][ct * 16 + lr] = (__bf16)acc[ct][i];
    __syncthreads();

    __bf16* out = (nc == 0) ? qb : (nc == 1) ? kb : vb;
    const int row = t >> 2, qtr = t & 3;
    const __bf16* srcp = &ytile[row >> 4][row & 15][qtr * 64];
    __bf16* dst = out + (size_t)(m0 + row) * 256 + qtr * 64;
    #pragma unroll
    for (int j = 0; j < 8; ++j)
        *(bf16x8*)(dst + j * 8) = *(const bf16x8*)(srcp + j * 8);
}

// ---------------- Kernel 3: VW^T = (V_h @ wout_h)^T per (window, head) ----------------
// grid (96, 8), 256 thr. Output vwt[(bb*8+h)*32 + d][m] bf16 — contiguous in m.
// D = A*B with A = wout_h^T [32 x 32], B = V_h^T [32 x 320] (read from row-major vb).
__global__ __launch_bounds__(256) void k_vw(
    const __bf16* __restrict__ vb, const float* __restrict__ wout,
    __bf16* __restrict__ vwt)
{
    const int t = threadIdx.x, wave = t >> 6, lane = t & 63;
    const int lr = lane & 15, lg = lane >> 4;
    const int bb = blockIdx.x, h = blockIdx.y;
    const int m0 = wave * 80;                 // wave covers 80 m-columns

    // A-fragments: A[row=d(tile)][k] = wout[(h*32 + k)*32 + rt*16 + row]
    bf16x8 afr[2];
    #pragma unroll
    for (int rt = 0; rt < 2; ++rt)
        #pragma unroll
        for (int j = 0; j < 8; ++j)
            afr[rt][j] = (__bf16)wout[(h * 32 + lg * 8 + j) * 32 + rt * 16 + lr];

    const __bf16* vbase = vb + ((size_t)bb * NTOK) * INNER + h * DH + lg * 8;
    __bf16* obase = vwt + ((size_t)(bb * HEADS + h) * DH) * NTOK;

    #pragma unroll
    for (int mt = 0; mt < 5; ++mt) {
        const int m = m0 + mt * 16 + lr;
        const bf16x8 bfr = *(const bf16x8*)(vbase + (size_t)m * INNER);  // B[k][col=m]
        #pragma unroll
        for (int rt = 0; rt < 2; ++rt) {
            const f32x4 d4 = __builtin_amdgcn_mfma_f32_16x16x32_bf16(
                afr[rt], bfr, (f32x4){0.f, 0.f, 0.f, 0.f}, 0, 0, 0);
            #pragma unroll
            for (int i = 0; i < 4; ++i) {
                const int drow = rt * 16 + lg * 4 + i;
                obase[(size_t)drow * NTOK + m0 + mt * 16 + lr] = (__bf16)d4[i];
            }
        }
    }
}

// ---------------- Kernel 4: fused attention + projection ----------------
// grid (NTOK/32, BWIN), 128 thr = 2 waves; wave owns 16 q rows; loops all 8 heads,
// accumulating projected 32-dim output. No __syncthreads (P LDS is wave-private).
__global__ __launch_bounds__(128) void k_attn_fused(
    const __bf16* __restrict__ qb, const __bf16* __restrict__ kb,
    const __bf16* __restrict__ vwt, const float* __restrict__ ctx,
    float* __restrict__ out)
{
    __shared__ __bf16 plds[2][16][MPAD];
    const int t = threadIdx.x;
    const int wave = t >> 6, lane = t & 63;
    const int lr = lane & 15, lg = lane >> 4;
    const int nw = blockIdx.x * 32 + wave * 16;
    const int bb = blockIdx.y;

    f32x4 o0 = {0.f, 0.f, 0.f, 0.f}, o1 = {0.f, 0.f, 0.f, 0.f};

    for (int h = 0; h < HEADS; ++h) {
        // Q fragment for this head
        const bf16x8 qfrag =
            *(const bf16x8*)(qb + ((size_t)(bb * NTOK + nw + lr)) * INNER + h * DH + lg * 8);

        // QK^T: 20 column tiles of 16 keys
        f32x4 s[20];
        const __bf16* kbase = kb + ((size_t)(bb * NTOK)) * INNER + h * DH + lg * 8;
        #pragma unroll
        for (int mt = 0; mt < 20; ++mt) {
            const bf16x8 kfrag = *(const bf16x8*)(kbase + (size_t)(mt * 16 + lr) * INNER);
            s[mt] = __builtin_amdgcn_mfma_f32_16x16x32_bf16(qfrag, kfrag,
                                                            (f32x4){0.f, 0.f, 0.f, 0.f}, 0, 0, 0);
        }

        // bias add at D-fragment positions
        const float* cbase = ctx + ((size_t)(bb * NTOK + nw)) * CTXW + h * NTOK;
        #pragma unroll
        for (int i = 0; i < 4; ++i) {
            const float* crow = cbase + (size_t)(lg * 4 + i) * CTXW + lr;
            #pragma unroll
            for (int mt = 0; mt < 20; ++mt) s[mt][i] += crow[mt * 16];
        }

        // softmax over m (rows live in lanes lr of each lg group? no: per-row over 20*16 m)
        float rmax[4], rsum[4], rinv[4];
        #pragma unroll
        for (int i = 0; i < 4; ++i) rmax[i] = -3e38f;
        #pragma unroll
        for (int mt = 0; mt < 20; ++mt)
            #pragma unroll
            for (int i = 0; i < 4; ++i) rmax[i] = fmaxf(rmax[i], s[mt][i]);
        #pragma unroll
        for (int i = 0; i < 4; ++i)
            #pragma unroll
            for (int o = 1; o <= 8; o <<= 1) rmax[i] = fmaxf(rmax[i], __shfl_xor(rmax[i], o));
        #pragma unroll
        for (int i = 0; i < 4; ++i) rsum[i] = 0.f;
        #pragma unroll
        for (int mt = 0; mt < 20; ++mt)
            #pragma unroll
            for (int i = 0; i < 4; ++i) {
                const float e = __expf(s[mt][i] - rmax[i]);
                s[mt][i] = e;
                rsum[i] += e;
            }
        #pragma unroll
        for (int i = 0; i < 4; ++i) {
            #pragma unroll
            for (int o = 1; o <= 8; o <<= 1) rsum[i] += __shfl_xor(rsum[i], o);
            rinv[i] = 1.0f / rsum[i];
        }

        // P (normalized, bf16) -> wave-private LDS strip [n][m]
        #pragma unroll
        for (int mt = 0; mt < 20; ++mt)
            #pragma unroll
            for (int i = 0; i < 4; ++i)
                plds[wave][lg * 4 + i][mt * 16 + lr] = (__bf16)(s[mt][i] * rinv[i]);

        // PV' : O += P @ VW_h  (K=320 in 10 steps; cols 0..15 -> o0, 16..31 -> o1)
        const __bf16* vwb = vwt + ((size_t)(bb * HEADS + h) * DH) * NTOK;
        #pragma unroll
        for (int ks = 0; ks < 10; ++ks) {
            const bf16x8 pfrag = *(const bf16x8*)&plds[wave][lr][ks * 32 + lg * 8];
            const bf16x8 b0 = *(const bf16x8*)(vwb + (size_t)lr * NTOK + ks * 32 + lg * 8);
            const bf16x8 b1 = *(const bf16x8*)(vwb + (size_t)(16 + lr) * NTOK + ks * 32 + lg * 8);
            o0 = __builtin_amdgcn_mfma_f32_16x16x32_bf16(pfrag, b0, o0, 0, 0, 0);
            o1 = __builtin_amdgcn_mfma_f32_16x16x32_bf16(pfrag, b1, o1, 0, 0, 0);
        }
    }

    // epilogue: scatter 'b h (l w1 w2) d -> b l x y w1 w2 (h d)' projected rows
    const int b_idx = bb / 48, x_idx = (bb % 48) >> 3, y_idx = bb & 7;
    #pragma unroll
    for (int i = 0; i < 4; ++i) {
        const int n = nw + lg * 4 + i;
        const int l_idx = n >> 6, w1_idx = (n >> 3) & 7, w2_idx = n & 7;
        const size_t dst =
            ((((((size_t)b_idx * 5 + l_idx) * 6 + x_idx) * 8 + y_idx) * 8 + w1_idx) * 8 + w2_idx) * (size_t)DH;
        out[dst + lr]      = o0[i];
        out[dst + 16 + lr] = o1[i];
    }
}

extern "C" void kernel_launch(void* const* d_in, const int* in_sizes, int n_in,
                              void* d_out, int out_size, void* d_ws, size_t ws_size,
                              hipStream_t stream) {
    const float* x    = (const float*)d_in[0];
    const float* ctx  = (const float*)d_in[1];
    const float* wq   = (const float*)d_in[2];
    const float* wkv  = (const float*)d_in[3];
    const float* wout = (const float*)d_in[4];
    const float* ln_g = (const float*)d_in[5];
    const float* ln_b = (const float*)d_in[6];
    float* out = (float*)d_out;

    // workspace (all bf16): qb|kb|vb|yb (SEG each), wT (768*256), vwt (SEG)
    const size_t SEG = (size_t)BWIN * NTOK * INNER;  // 7,864,320 elements
    __bf16* qb  = (__bf16*)d_ws;
    __bf16* kb  = qb + SEG;
    __bf16* vb  = kb + SEG;
    __bf16* yb  = vb + SEG;
    __bf16* wT  = yb + SEG;
    __bf16* vwt = wT + 768 * 256;

    const int ROWS = BWIN * NTOK;  // 30720
    k_castw<<<768, 256, 0, stream>>>(wq, wkv, wT);
    k_ln<<<ROWS / 4, 256, 0, stream>>>(x, ln_g, ln_b, yb);
    k_qkv<<<dim3(ROWS / 64, 3), 256, 0, stream>>>(yb, wT, qb, kb, vb);
    k_vw<<<dim3(BWIN, HEADS), 256, 0, stream>>>(vb, wout, vwt);
    k_attn_fused<<<dim3(NTOK / 32, BWIN), 128, 0, stream>>>(qb, kb, vwt, ctx, out);
}

// Round 6
// 196.330 us; speedup vs baseline: 8.5621x; 1.4050x over previous
//
#include <hip/hip_runtime.h>
#include <hip/hip_bf16.h>

// Problem constants
#define BWIN 96      // b*gx*gy = 2*6*8
#define NTOK 320     // l*w1*w2 = 5*8*8
#define DIMX 256
#define HEADS 8
#define DH 32
#define INNER 256
#define CTXW 2560    // HEADS*NTOK
#define MPAD 328     // padded m-stride for P LDS strips

typedef __bf16 bf16x8 __attribute__((ext_vector_type(8)));
typedef __bf16 bf16x4 __attribute__((ext_vector_type(4)));
typedef float f32x4 __attribute__((ext_vector_type(4)));

// ---------------- Kernel 1: fused weight-cast + LayerNorm ----------------
// blocks 0..767: cast wq|wkv -> wT[768][256] bf16 (col-major-K, contiguous d)
// blocks 768+ : LN rows (4 rows per block, one per wave)
__global__ __launch_bounds__(256) void k_pre(
    const float* __restrict__ wq, const float* __restrict__ wkv,
    const float* __restrict__ x, const float* __restrict__ g,
    const float* __restrict__ bt, __bf16* __restrict__ wT,
    __bf16* __restrict__ y)
{
    const int t = threadIdx.x;
    if (blockIdx.x < 768) {
        const int col = blockIdx.x;
        float v;
        if (col < 256)      v = wq[t * 256 + col];
        else if (col < 512) v = wkv[t * 512 + (col - 256)];
        else                v = wkv[t * 512 + 256 + (col - 512)];
        wT[(size_t)col * 256 + t] = (__bf16)v;
        return;
    }
    const int wave = t >> 6, lane = t & 63;
    const int row = (blockIdx.x - 768) * 4 + wave;
    const int bb = row / NTOK, n = row % NTOK;
    const int b_idx = bb / 48, x_idx = (bb % 48) >> 3, y_idx = bb & 7;
    const int l_idx = n >> 6, w1_idx = (n >> 3) & 7, w2_idx = n & 7;
    const size_t src =
        ((((((size_t)b_idx * 5 + l_idx) * 6 + x_idx) * 8 + y_idx) * 8 + w1_idx) * 8 + w2_idx) * (size_t)DIMX;

    const float4 xv = *(const float4*)(x + src + lane * 4);
    float s = xv.x + xv.y + xv.z + xv.w;
    float ss = xv.x * xv.x + xv.y * xv.y + xv.z * xv.z + xv.w * xv.w;
    #pragma unroll
    for (int o = 32; o > 0; o >>= 1) {
        s += __shfl_xor(s, o);
        ss += __shfl_xor(ss, o);
    }
    const float mu = s * (1.0f / DIMX);
    const float var = ss * (1.0f / DIMX) - mu * mu;
    const float rsig = rsqrtf(var + 1e-5f);
    const float4 g4 = *(const float4*)(g + lane * 4);
    const float4 b4 = *(const float4*)(bt + lane * 4);
    bf16x4 yo;
    yo[0] = (__bf16)((xv.x - mu) * rsig * g4.x + b4.x);
    yo[1] = (__bf16)((xv.y - mu) * rsig * g4.y + b4.y);
    yo[2] = (__bf16)((xv.z - mu) * rsig * g4.z + b4.z);
    yo[3] = (__bf16)((xv.w - mu) * rsig * g4.w + b4.w);
    *(bf16x4*)(y + (size_t)row * DIMX + lane * 4) = yo;
}

// ---------------- Kernel 2: QKV GEMM, 128x128 tile, LDS-staged ----------------
// grid (240, 6). Computes D' = wT_cols x y_rows via mfma(wfrag, yfrag) so each
// lane holds 4 consecutive OUTPUT COLUMNS -> direct b64 stores, no repack.
// Wave grid 2(M-row)x2(N-col): wave handles 64 rows x 64 cols.
__global__ __launch_bounds__(256) void k_qkv(
    const __bf16* __restrict__ y, const __bf16* __restrict__ wT,
    __bf16* __restrict__ qb, __bf16* __restrict__ kb, __bf16* __restrict__ vb)
{
    __shared__ __bf16 yls[128][40];   // rows x (32k + 8 pad)
    __shared__ __bf16 wls[128][40];   // cols x (32k + 8 pad)
    const int t = threadIdx.x, wave = t >> 6, lane = t & 63;
    const int lr = lane & 15, lg = lane >> 4;
    const int wm = wave & 1, wn = wave >> 1;
    const int rbase = blockIdx.x * 128;
    const int cbase = blockIdx.y * 128;

    f32x4 acc[4][4];
    #pragma unroll
    for (int im = 0; im < 4; ++im)
        #pragma unroll
        for (int jn = 0; jn < 4; ++jn) acc[im][jn] = (f32x4){0.f, 0.f, 0.f, 0.f};

    const int srow = t >> 1, sseg = (t & 1) * 16;
    #pragma unroll
    for (int ks = 0; ks < 8; ++ks) {
        __syncthreads();   // protect previous iteration's reads
        #pragma unroll
        for (int j = 0; j < 2; ++j) {
            *(bf16x8*)&yls[srow][sseg + j * 8] =
                *(const bf16x8*)(y + (size_t)(rbase + srow) * DIMX + ks * 32 + sseg + j * 8);
            *(bf16x8*)&wls[srow][sseg + j * 8] =
                *(const bf16x8*)(wT + (size_t)(cbase + srow) * DIMX + ks * 32 + sseg + j * 8);
        }
        __syncthreads();

        bf16x8 yfr[4], wfr[4];
        #pragma unroll
        for (int jn = 0; jn < 4; ++jn) yfr[jn] = *(const bf16x8*)&yls[wm * 64 + jn * 16 + lr][lg * 8];
        #pragma unroll
        for (int im = 0; im < 4; ++im) wfr[im] = *(const bf16x8*)&wls[wn * 64 + im * 16 + lr][lg * 8];
        #pragma unroll
        for (int im = 0; im < 4; ++im)
            #pragma unroll
            for (int jn = 0; jn < 4; ++jn)
                acc[im][jn] = __builtin_amdgcn_mfma_f32_16x16x32_bf16(wfr[im], yfr[jn], acc[im][jn], 0, 0, 0);
    }

    // store: lane holds cols g..g+3 (i=0..3) at row (rbase + wm*64 + jn*16 + lr)
    #pragma unroll
    for (int im = 0; im < 4; ++im) {
        const int g = cbase + wn * 64 + im * 16 + lg * 4;
        __bf16* buf = (g < 256) ? qb : (g < 512) ? kb : vb;
        const int gc = g & 255;
        #pragma unroll
        for (int jn = 0; jn < 4; ++jn) {
            const int row = rbase + wm * 64 + jn * 16 + lr;
            bf16x4 p;
            #pragma unroll
            for (int i = 0; i < 4; ++i) p[i] = (__bf16)acc[im][jn][i];
            *(bf16x4*)(buf + (size_t)row * INNER + gc) = p;
        }
    }
}

// ---------------- Kernel 3: VW^T = (V_h @ wout_h)^T per (window, head) ----------------
__global__ __launch_bounds__(256) void k_vw(
    const __bf16* __restrict__ vb, const float* __restrict__ wout,
    __bf16* __restrict__ vwt)
{
    const int t = threadIdx.x, wave = t >> 6, lane = t & 63;
    const int lr = lane & 15, lg = lane >> 4;
    const int bb = blockIdx.x, h = blockIdx.y;
    const int m0 = wave * 80;

    bf16x8 afr[2];
    #pragma unroll
    for (int rt = 0; rt < 2; ++rt)
        #pragma unroll
        for (int j = 0; j < 8; ++j)
            afr[rt][j] = (__bf16)wout[(h * 32 + lg * 8 + j) * 32 + rt * 16 + lr];

    const __bf16* vbase = vb + ((size_t)bb * NTOK) * INNER + h * DH + lg * 8;
    __bf16* obase = vwt + ((size_t)(bb * HEADS + h) * DH) * NTOK;

    #pragma unroll
    for (int mt = 0; mt < 5; ++mt) {
        const int m = m0 + mt * 16 + lr;
        const bf16x8 bfr = *(const bf16x8*)(vbase + (size_t)m * INNER);
        #pragma unroll
        for (int rt = 0; rt < 2; ++rt) {
            const f32x4 d4 = __builtin_amdgcn_mfma_f32_16x16x32_bf16(
                afr[rt], bfr, (f32x4){0.f, 0.f, 0.f, 0.f}, 0, 0, 0);
            #pragma unroll
            for (int i = 0; i < 4; ++i) {
                const int drow = rt * 16 + lg * 4 + i;
                obase[(size_t)drow * NTOK + m0 + mt * 16 + lr] = (__bf16)d4[i];
            }
        }
    }
}

// ---------------- Kernel 4: fused attention + projection (swapped-operand) ----------------
// grid (10, 96), 128 thr = 2 waves, wave owns 16 q-rows (q = nw + lr).
// S^T = mfma(K,Q): lane holds m = mt*16+lg*4+i (4 consecutive), q = lr.
// O^T = mfma(VW^T, P^T): lane holds d = lg*4+i (+16), q = lr.
__global__ __launch_bounds__(128) void k_attn(
    const __bf16* __restrict__ qb, const __bf16* __restrict__ kb,
    const __bf16* __restrict__ vwt, const float* __restrict__ ctx,
    float* __restrict__ out)
{
    __shared__ __bf16 plds[2][16][MPAD];   // [wave][q-local][m]
    const int t = threadIdx.x;
    const int wave = t >> 6, lane = t & 63;
    const int lr = lane & 15, lg = lane >> 4;
    const int nw = blockIdx.x * 32 + wave * 16;
    const int bb = blockIdx.y;

    f32x4 o0 = {0.f, 0.f, 0.f, 0.f}, o1 = {0.f, 0.f, 0.f, 0.f};
    const float* crow = ctx + ((size_t)(bb * NTOK + nw + lr)) * CTXW;  // this lane's q-row

    for (int h = 0; h < HEADS; ++h) {
        // Q as B-fragment (8 contiguous d)
        const bf16x8 qfrag =
            *(const bf16x8*)(qb + ((size_t)(bb * NTOK + nw + lr)) * INNER + h * DH + lg * 8);

        // S^T tiles: A = K rows (16 keys), B = Q
        f32x4 s[20];
        const __bf16* kbase = kb + ((size_t)(bb * NTOK)) * INNER + h * DH + lg * 8;
        #pragma unroll
        for (int mt = 0; mt < 20; ++mt) {
            const bf16x8 kfrag = *(const bf16x8*)(kbase + (size_t)(mt * 16 + lr) * INNER);
            s[mt] = __builtin_amdgcn_mfma_f32_16x16x32_bf16(kfrag, qfrag,
                                                            (f32x4){0.f, 0.f, 0.f, 0.f}, 0, 0, 0);
        }

        // bias: lane's q-row, 4 consecutive m -> float4
        const float* ch = crow + h * NTOK;
        #pragma unroll
        for (int mt = 0; mt < 20; ++mt) {
            const float4 c4 = *(const float4*)(ch + mt * 16 + lg * 4);
            s[mt][0] += c4.x; s[mt][1] += c4.y; s[mt][2] += c4.z; s[mt][3] += c4.w;
        }

        // softmax over m: local 80 + lanes {+16,+32}
        float mx = -3e38f;
        #pragma unroll
        for (int mt = 0; mt < 20; ++mt)
            #pragma unroll
            for (int i = 0; i < 4; ++i) mx = fmaxf(mx, s[mt][i]);
        mx = fmaxf(mx, __shfl_xor(mx, 16));
        mx = fmaxf(mx, __shfl_xor(mx, 32));
        float sum = 0.f;
        #pragma unroll
        for (int mt = 0; mt < 20; ++mt)
            #pragma unroll
            for (int i = 0; i < 4; ++i) {
                const float e = __expf(s[mt][i] - mx);
                s[mt][i] = e;
                sum += e;
            }
        sum += __shfl_xor(sum, 16);
        sum += __shfl_xor(sum, 32);
        const float rinv = 1.0f / sum;

        // P^T -> LDS [q][m]: 4 consecutive m per (mt) -> b64 writes
        #pragma unroll
        for (int mt = 0; mt < 20; ++mt) {
            bf16x4 p4;
            #pragma unroll
            for (int i = 0; i < 4; ++i) p4[i] = (__bf16)(s[mt][i] * rinv);
            *(bf16x4*)&plds[wave][lr][mt * 16 + lg * 4] = p4;
        }

        // O^T += VW^T x P^T  (A = VW^T d-rows, B = P^T)
        const __bf16* vwb = vwt + ((size_t)(bb * HEADS + h) * DH) * NTOK;
        #pragma unroll
        for (int ks = 0; ks < 10; ++ks) {
            const bf16x8 pfrag = *(const bf16x8*)&plds[wave][lr][ks * 32 + lg * 8];
            const bf16x8 vf0 = *(const bf16x8*)(vwb + (size_t)lr * NTOK + ks * 32 + lg * 8);
            const bf16x8 vf1 = *(const bf16x8*)(vwb + (size_t)(16 + lr) * NTOK + ks * 32 + lg * 8);
            o0 = __builtin_amdgcn_mfma_f32_16x16x32_bf16(vf0, pfrag, o0, 0, 0, 0);
            o1 = __builtin_amdgcn_mfma_f32_16x16x32_bf16(vf1, pfrag, o1, 0, 0, 0);
        }
    }

    // epilogue: lane's token n = nw + lr; two float4 stores (d = lg*4.., 16+lg*4..)
    const int n = nw + lr;
    const int b_idx = bb / 48, x_idx = (bb % 48) >> 3, y_idx = bb & 7;
    const int l_idx = n >> 6, w1_idx = (n >> 3) & 7, w2_idx = n & 7;
    const size_t dst =
        ((((((size_t)b_idx * 5 + l_idx) * 6 + x_idx) * 8 + y_idx) * 8 + w1_idx) * 8 + w2_idx) * (size_t)DH;
    *(f32x4*)(out + dst + lg * 4)      = o0;
    *(f32x4*)(out + dst + 16 + lg * 4) = o1;
}

extern "C" void kernel_launch(void* const* d_in, const int* in_sizes, int n_in,
                              void* d_out, int out_size, void* d_ws, size_t ws_size,
                              hipStream_t stream) {
    const float* x    = (const float*)d_in[0];
    const float* ctx  = (const float*)d_in[1];
    const float* wq   = (const float*)d_in[2];
    const float* wkv  = (const float*)d_in[3];
    const float* wout = (const float*)d_in[4];
    const float* ln_g = (const float*)d_in[5];
    const float* ln_b = (const float*)d_in[6];
    float* out = (float*)d_out;

    // workspace (all bf16): qb|kb|vb|yb (SEG each), wT, vwt
    const size_t SEG = (size_t)BWIN * NTOK * INNER;  // 7,864,320 elements
    __bf16* qb  = (__bf16*)d_ws;
    __bf16* kb  = qb + SEG;
    __bf16* vb  = kb + SEG;
    __bf16* yb  = vb + SEG;
    __bf16* wT  = yb + SEG;
    __bf16* vwt = wT + 768 * 256;

    const int ROWS = BWIN * NTOK;  // 30720
    k_pre<<<768 + ROWS / 4, 256, 0, stream>>>(wq, wkv, x, ln_g, ln_b, wT, yb);
    k_qkv<<<dim3(ROWS / 128, 6), 256, 0, stream>>>(yb, wT, qb, kb, vb);
    k_vw<<<dim3(BWIN, HEADS), 256, 0, stream>>>(vb, wout, vwt);
    k_attn<<<dim3(NTOK / 32, BWIN), 128, 0, stream>>>(qb, kb, vwt, ctx, out);
}